// Round 1
// baseline (335.077 us; speedup 1.0000x reference)
//
#include <hip/hip_runtime.h>

#define NN 50000
#define NE 150000

// ---------- K1: degree histograms (self-loop handled as +1 at read) ----------
__global__ __launch_bounds__(256) void k_deg(const int* __restrict__ src,
                                             const int* __restrict__ dst,
                                             int* __restrict__ deg_out,
                                             int* __restrict__ deg_in) {
    int e = blockIdx.x * 256 + threadIdx.x;
    if (e < NE) {
        atomicAdd(&deg_out[src[e]], 1);
        atomicAdd(&deg_in[dst[e]], 1);
    }
}

// ---------- K2: conv1 aggregation (+self loops) and c_m coefficient ----------
// c_m = din_m + sum_{e: src(e)=m} din_{dst(e)}   (din = deg_in^{-1/2})
__global__ __launch_bounds__(256) void k_agg1_c(const float* __restrict__ x,
                                                const int* __restrict__ src,
                                                const int* __restrict__ dst,
                                                const int* __restrict__ deg_out,
                                                const int* __restrict__ deg_in,
                                                float* __restrict__ agg1,
                                                float* __restrict__ c) {
    int i = blockIdx.x * 256 + threadIdx.x;
    if (i < NE) {
        int s = src[i], d = dst[i];
        float dout = rsqrtf((float)(deg_out[s] + 1));
        float dind = rsqrtf((float)(deg_in[d] + 1));
        #pragma unroll
        for (int j = 0; j < 4; j++)
            atomicAdd(&agg1[d * 4 + j], x[s * 4 + j] * dout);
        atomicAdd(&c[s], dind);
    } else if (i < NE + NN) {
        int n = i - NE;
        float dout = rsqrtf((float)(deg_out[n] + 1));
        float din  = rsqrtf((float)(deg_in[n] + 1));
        #pragma unroll
        for (int j = 0; j < 4; j++)
            atomicAdd(&agg1[n * 4 + j], x[n * 4 + j] * dout);
        atomicAdd(&c[n], din);
    }
}

// ---------- K3: conv1 matvec + relu, pre-scaled by deg_out^{-1/2} for conv2 ----------
__global__ __launch_bounds__(256) void k_conv1(const float* __restrict__ agg1,
                                               const float* __restrict__ W1,
                                               const float* __restrict__ b1,
                                               const int* __restrict__ deg_out,
                                               const int* __restrict__ deg_in,
                                               float* __restrict__ h1s) {
    int n = blockIdx.x * 256 + threadIdx.x;
    if (n >= NN) return;
    float a0 = agg1[n * 4 + 0], a1 = agg1[n * 4 + 1];
    float a2 = agg1[n * 4 + 2], a3 = agg1[n * 4 + 3];
    float din  = rsqrtf((float)(deg_in[n] + 1));
    float dout = rsqrtf((float)(deg_out[n] + 1));
    #pragma unroll
    for (int j = 0; j < 11; j++) {
        float y = a0 * W1[0 * 11 + j] + a1 * W1[1 * 11 + j] +
                  a2 * W1[2 * 11 + j] + a3 * W1[3 * 11 + j];
        y = fmaf(y, din, b1[j]);
        y = fmaxf(y, 0.f);
        h1s[n * 11 + j] = y * dout;
    }
}

// ---------- K4: conv2 aggregation (edge-weighted; self loops have ef=0 -> skip) ----------
__global__ __launch_bounds__(256) void k_agg2(const float* __restrict__ h1s,
                                              const float* __restrict__ ef,
                                              const int* __restrict__ src,
                                              const int* __restrict__ dst,
                                              float* __restrict__ agg2) {
    int e = blockIdx.x * 256 + threadIdx.x;
    if (e >= NE) return;
    int s = src[e], d = dst[e];
    #pragma unroll
    for (int j = 0; j < 11; j++)
        atomicAdd(&agg2[d * 11 + j], h1s[s * 11 + j] * ef[e * 11 + j]);
}

// ---------- K5: conv2 matvec+relu fused with weighted mean-reduction into t[512] ----------
#define NPB 64
__global__ __launch_bounds__(512) void k_conv2_reduce(const float* __restrict__ agg2,
                                                      const float* __restrict__ W2,
                                                      const float* __restrict__ b2,
                                                      const float* __restrict__ c,
                                                      const int* __restrict__ deg_out,
                                                      const int* __restrict__ deg_in,
                                                      float* __restrict__ t) {
    __shared__ float tile[NPB * 11];
    __shared__ float din_sh[NPB], w_sh[NPB];
    int n0 = blockIdx.x * NPB;
    int tid = threadIdx.x;
    for (int i = tid; i < NPB * 11; i += 512) {
        int gi = n0 * 11 + i;
        tile[i] = (gi < NN * 11) ? agg2[gi] : 0.f;
    }
    if (tid < NPB) {
        int node = n0 + tid;
        if (node < NN) {
            din_sh[tid] = rsqrtf((float)(deg_in[node] + 1));
            w_sh[tid]   = c[node] * rsqrtf((float)(deg_out[node] + 1)) * (1.0f / NN);
        } else { din_sh[tid] = 0.f; w_sh[tid] = 0.f; }
    }
    __syncthreads();
    float w[11];
    #pragma unroll
    for (int j = 0; j < 11; j++) w[j] = W2[j * 512 + tid];
    float bias = b2[tid];
    float acc = 0.f;
    for (int i = 0; i < NPB; i++) {
        float dot = 0.f;
        #pragma unroll
        for (int j = 0; j < 11; j++) dot = fmaf(tile[i * 11 + j], w[j], dot);
        float y = fmaxf(fmaf(dot, din_sh[i], bias), 0.f);
        acc = fmaf(w_sh[i], y, acc);
    }
    atomicAdd(&t[tid], acc);
}

// ---------- K6: g = t @ W3 + b3  (512x1024 matvec) ----------
__global__ __launch_bounds__(256) void k_g(const float* __restrict__ t,
                                           const float* __restrict__ W3,
                                           const float* __restrict__ b3,
                                           float* __restrict__ g) {
    __shared__ float ts[512];
    for (int i = threadIdx.x; i < 512; i += 256) ts[i] = t[i];
    __syncthreads();
    int o = blockIdx.x * 256 + threadIdx.x;  // 0..1023
    float acc = b3[o];
    for (int k = 0; k < 512; k++) acc = fmaf(ts[k], W3[k * 1024 + o], acc);
    g[o] = acc;
}

// ---------- K7: head layer-1 partial matvecs (bias/relu deferred) ----------
// grid 128 = oc(16) x kc(8); outputs 0..2047 -> hv_raw, 2048..4095 -> ha_raw
__global__ __launch_bounds__(256) void k_heads1(const float* __restrict__ g,
                                                const float* __restrict__ Wv1,
                                                const float* __restrict__ Wa1,
                                                float* __restrict__ hv_raw,
                                                float* __restrict__ ha_raw) {
    int b = blockIdx.x;
    int oc = b >> 3, kc = b & 7;
    int idx = oc * 256 + threadIdx.x;  // 0..4095
    int k0 = kc * 128;
    __shared__ float gs[128];
    if (threadIdx.x < 128) gs[threadIdx.x] = g[k0 + threadIdx.x];
    __syncthreads();
    const float* W; float* outp; int o;
    if (idx < 2048) { W = Wv1; outp = hv_raw; o = idx; }
    else            { W = Wa1; outp = ha_raw; o = idx - 2048; }
    float acc = 0.f;
    #pragma unroll 4
    for (int k = 0; k < 128; k++) acc = fmaf(gs[k], W[(size_t)(k0 + k) * 2048 + o], acc);
    atomicAdd(&outp[o], acc);
}

// ---------- K8: head layer-2: a partials (64 blocks) + v (1 block) ----------
__global__ __launch_bounds__(256) void k_heads2(const float* __restrict__ hv_raw,
                                                const float* __restrict__ bv1,
                                                const float* __restrict__ ha_raw,
                                                const float* __restrict__ ba1,
                                                const float* __restrict__ Wv2,
                                                const float* __restrict__ bv2,
                                                const float* __restrict__ Wa2,
                                                float* __restrict__ a_acc,
                                                float* __restrict__ v) {
    int b = blockIdx.x;
    int tid = threadIdx.x;
    if (b < 64) {
        int oc = b >> 4, kc = b & 15;
        int k0 = kc * 128;
        __shared__ float hs[128];
        if (tid < 128) hs[tid] = fmaxf(ha_raw[k0 + tid] + ba1[k0 + tid], 0.f);
        __syncthreads();
        int o = oc * 256 + tid;  // 0..1023
        if (o < 1000) {
            float acc = 0.f;
            #pragma unroll 4
            for (int k = 0; k < 128; k++)
                acc = fmaf(hs[k], Wa2[(size_t)(k0 + k) * 1000 + o], acc);
            atomicAdd(&a_acc[o], acc);
        }
    } else {
        __shared__ float red[256];
        float acc = 0.f;
        for (int k = tid; k < 2048; k += 256)
            acc = fmaf(fmaxf(hv_raw[k] + bv1[k], 0.f), Wv2[k], acc);
        red[tid] = acc;
        __syncthreads();
        for (int s = 128; s >= 1; s >>= 1) {
            if (tid < s) red[tid] += red[tid + s];
            __syncthreads();
        }
        if (tid == 0) *v = red[0] + bv2[0];
    }
}

// ---------- K9: final: out = v + (a - mean(a)) ----------
__global__ __launch_bounds__(1024) void k_final(const float* __restrict__ a_acc,
                                                const float* __restrict__ ba2,
                                                const float* __restrict__ vptr,
                                                float* __restrict__ out) {
    __shared__ float red[1024];
    int tid = threadIdx.x;
    float ai = (tid < 1000) ? a_acc[tid] + ba2[tid] : 0.f;
    red[tid] = ai;
    __syncthreads();
    for (int s = 512; s >= 1; s >>= 1) {
        if (tid < s) red[tid] += red[tid + s];
        __syncthreads();
    }
    float amean = red[0] * (1.0f / 1000.0f);
    if (tid < 1000) out[tid] = vptr[0] + ai - amean;
}

extern "C" void kernel_launch(void* const* d_in, const int* in_sizes, int n_in,
                              void* d_out, int out_size, void* d_ws, size_t ws_size,
                              hipStream_t stream) {
    const float* x   = (const float*)d_in[0];
    const float* ef  = (const float*)d_in[1];
    const float* W1  = (const float*)d_in[2];
    const float* b1  = (const float*)d_in[3];
    const float* W2  = (const float*)d_in[4];
    const float* b2  = (const float*)d_in[5];
    const float* W3  = (const float*)d_in[6];
    const float* b3  = (const float*)d_in[7];
    const float* Wv1 = (const float*)d_in[8];
    const float* bv1 = (const float*)d_in[9];
    const float* Wv2 = (const float*)d_in[10];
    const float* bv2 = (const float*)d_in[11];
    const float* Wa1 = (const float*)d_in[12];
    const float* ba1 = (const float*)d_in[13];
    const float* Wa2 = (const float*)d_in[14];
    const float* ba2 = (const float*)d_in[15];
    const int*   src = (const int*)d_in[16];
    const int*   dst = (const int*)d_in[17];
    float* out = (float*)d_out;

    char* ws = (char*)d_ws;
    size_t off = 0;
    auto alloc = [&](size_t bytes) -> void* {
        void* p = ws + off;
        off = (off + bytes + 255) & ~(size_t)255;
        return p;
    };
    int*   deg_out = (int*)  alloc(NN * 4);
    int*   deg_in  = (int*)  alloc(NN * 4);
    float* c       = (float*)alloc(NN * 4);
    float* agg1    = (float*)alloc((size_t)NN * 4 * 4);
    float* agg2    = (float*)alloc((size_t)NN * 11 * 4);
    float* t       = (float*)alloc(512 * 4);
    float* hv_raw  = (float*)alloc(2048 * 4);
    float* ha_raw  = (float*)alloc(2048 * 4);
    float* a_acc   = (float*)alloc(1024 * 4);
    size_t zero_bytes = off;   // everything above must start at 0
    float* h1s     = (float*)alloc((size_t)NN * 11 * 4);
    // (g, v below)
    float* g       = (float*)alloc(1024 * 4);
    float* v       = (float*)alloc(256);

    hipMemsetAsync(d_ws, 0, zero_bytes, stream);

    k_deg<<<(NE + 255) / 256, 256, 0, stream>>>(src, dst, deg_out, deg_in);
    k_agg1_c<<<(NE + NN + 255) / 256, 256, 0, stream>>>(x, src, dst, deg_out, deg_in, agg1, c);
    k_conv1<<<(NN + 255) / 256, 256, 0, stream>>>(agg1, W1, b1, deg_out, deg_in, h1s);
    k_agg2<<<(NE + 255) / 256, 256, 0, stream>>>(h1s, ef, src, dst, agg2);
    k_conv2_reduce<<<(NN + NPB - 1) / NPB, 512, 0, stream>>>(agg2, W2, b2, c, deg_out, deg_in, t);
    k_g<<<4, 256, 0, stream>>>(t, W3, b3, g);
    k_heads1<<<128, 256, 0, stream>>>(g, Wv1, Wa1, hv_raw, ha_raw);
    k_heads2<<<65, 256, 0, stream>>>(hv_raw, bv1, ha_raw, ba1, Wv2, bv2, Wa2, a_acc, v);
    k_final<<<1, 1024, 0, stream>>>(a_acc, ba2, v, out);
}

// Round 2
// 288.500 us; speedup vs baseline: 1.1614x; 1.1614x over previous
//
#include <hip/hip_runtime.h>

#define NN 50000
#define NE 150000

// ---------- K1: degree histograms (self-loop handled as +1 at read) ----------
__global__ __launch_bounds__(256) void k_deg(const int* __restrict__ src,
                                             const int* __restrict__ dst,
                                             int* __restrict__ deg_out,
                                             int* __restrict__ deg_in) {
    int e = blockIdx.x * 256 + threadIdx.x;
    if (e < NE) {
        atomicAdd(&deg_out[src[e]], 1);
        atomicAdd(&deg_in[dst[e]], 1);
    }
}

// ---------- K2: exclusive scan of deg_in -> rowptr (single block) ----------
__global__ __launch_bounds__(1024) void k_scan(const int* __restrict__ deg_in,
                                               int* __restrict__ rowptr) {
    __shared__ int bsum[1024];
    const int CH = (NN + 1023) / 1024;  // 49
    int tid = threadIdx.x;
    int base = tid * CH;
    int s = 0;
    for (int i = 0; i < CH; i++) {
        int idx = base + i;
        if (idx < NN) s += deg_in[idx];
    }
    bsum[tid] = s;
    __syncthreads();
    // Hillis-Steele inclusive scan of block sums
    for (int off = 1; off < 1024; off <<= 1) {
        int v = (tid >= off) ? bsum[tid - off] : 0;
        __syncthreads();
        bsum[tid] += v;
        __syncthreads();
    }
    int running = (tid == 0) ? 0 : bsum[tid - 1];
    for (int i = 0; i < CH; i++) {
        int idx = base + i;
        if (idx < NN) {
            rowptr[idx] = running;
            running += deg_in[idx];
        }
    }
    if (tid == 0) rowptr[NN] = NE;
}

// ---------- K3: scatter edge ids into dst-sorted CSR buckets ----------
__global__ __launch_bounds__(256) void k_scatter(const int* __restrict__ dst,
                                                 const int* __restrict__ rowptr,
                                                 int* __restrict__ cursor,
                                                 int* __restrict__ eidx) {
    int e = blockIdx.x * 256 + threadIdx.x;
    if (e >= NE) return;
    int d = dst[e];
    int pos = rowptr[d] + atomicAdd(&cursor[d], 1);
    eidx[pos] = e;
}

// ---------- K4: conv1 via CSR gather + fused 4->11 matvec/relu, + c atomics ----------
// h1s[n] = relu((agg1_n @ W1) * din_n + b1) * dout_n
// c[m]  += din_n for each edge m->n, plus din_m for self loop
__global__ __launch_bounds__(256) void k_conv1g(const float* __restrict__ x,
                                                const int* __restrict__ src,
                                                const int* __restrict__ eidx,
                                                const int* __restrict__ rowptr,
                                                const int* __restrict__ deg_out,
                                                const int* __restrict__ deg_in,
                                                const float* __restrict__ W1,
                                                const float* __restrict__ b1,
                                                float* __restrict__ h1s,
                                                float* __restrict__ c) {
    int n = blockIdx.x * 256 + threadIdx.x;
    if (n >= NN) return;
    float din  = rsqrtf((float)(deg_in[n] + 1));
    float dout = rsqrtf((float)(deg_out[n] + 1));
    // self-loop contribution
    const float4 xn = ((const float4*)x)[n];
    float a0 = xn.x * dout, a1 = xn.y * dout, a2 = xn.z * dout, a3 = xn.w * dout;
    int beg = rowptr[n], end = rowptr[n + 1];
    for (int p = beg; p < end; p++) {
        int e = eidx[p];
        int s = src[e];
        float ds = rsqrtf((float)(deg_out[s] + 1));
        float4 xs = ((const float4*)x)[s];
        a0 = fmaf(xs.x, ds, a0);
        a1 = fmaf(xs.y, ds, a1);
        a2 = fmaf(xs.z, ds, a2);
        a3 = fmaf(xs.w, ds, a3);
        atomicAdd(&c[s], din);
    }
    atomicAdd(&c[n], din);  // self loop
    #pragma unroll
    for (int j = 0; j < 11; j++) {
        float y = a0 * W1[0 * 11 + j] + a1 * W1[1 * 11 + j] +
                  a2 * W1[2 * 11 + j] + a3 * W1[3 * 11 + j];
        y = fmaxf(fmaf(y, din, b1[j]), 0.f);
        h1s[n * 11 + j] = y * dout;
    }
}

// ---------- K5: conv2 aggregation via CSR gather (self loops ef=0 -> skip) ----------
// thread = (node, feature j); 23 nodes per 256-thread block
__global__ __launch_bounds__(256) void k_agg2g(const float* __restrict__ h1s,
                                               const float* __restrict__ ef,
                                               const int* __restrict__ src,
                                               const int* __restrict__ eidx,
                                               const int* __restrict__ rowptr,
                                               float* __restrict__ agg2) {
    int tid = threadIdx.x;
    if (tid >= 253) return;
    int n = blockIdx.x * 23 + tid / 11;
    int j = tid % 11;
    if (n >= NN) return;
    int beg = rowptr[n], end = rowptr[n + 1];
    float acc = 0.f;
    for (int p = beg; p < end; p++) {
        int e = eidx[p];
        int s = src[e];
        acc = fmaf(h1s[s * 11 + j], ef[e * 11 + j], acc);
    }
    agg2[n * 11 + j] = acc;
}

// ---------- K6: conv2 matvec+relu fused with weighted mean-reduction into t[512] ----------
#define NPB 64
__global__ __launch_bounds__(512) void k_conv2_reduce(const float* __restrict__ agg2,
                                                      const float* __restrict__ W2,
                                                      const float* __restrict__ b2,
                                                      const float* __restrict__ c,
                                                      const int* __restrict__ deg_out,
                                                      const int* __restrict__ deg_in,
                                                      float* __restrict__ t) {
    __shared__ float tile[NPB * 11];
    __shared__ float din_sh[NPB], w_sh[NPB];
    int n0 = blockIdx.x * NPB;
    int tid = threadIdx.x;
    for (int i = tid; i < NPB * 11; i += 512) {
        int gi = n0 * 11 + i;
        tile[i] = (gi < NN * 11) ? agg2[gi] : 0.f;
    }
    if (tid < NPB) {
        int node = n0 + tid;
        if (node < NN) {
            din_sh[tid] = rsqrtf((float)(deg_in[node] + 1));
            w_sh[tid]   = c[node] * rsqrtf((float)(deg_out[node] + 1)) * (1.0f / NN);
        } else { din_sh[tid] = 0.f; w_sh[tid] = 0.f; }
    }
    __syncthreads();
    float w[11];
    #pragma unroll
    for (int j = 0; j < 11; j++) w[j] = W2[j * 512 + tid];
    float bias = b2[tid];
    float acc = 0.f;
    for (int i = 0; i < NPB; i++) {
        float dot = 0.f;
        #pragma unroll
        for (int j = 0; j < 11; j++) dot = fmaf(tile[i * 11 + j], w[j], dot);
        float y = fmaxf(fmaf(dot, din_sh[i], bias), 0.f);
        acc = fmaf(w_sh[i], y, acc);
    }
    atomicAdd(&t[tid], acc);
}

// ---------- K7: g = t @ W3 + b3  (512x1024 matvec, k-split 16 ways) ----------
__global__ __launch_bounds__(256) void k_g(const float* __restrict__ t,
                                           const float* __restrict__ W3,
                                           const float* __restrict__ b3,
                                           float* __restrict__ g) {
    int b = blockIdx.x;          // 64 = 4 oc x 16 kc
    int oc = b & 3, kc = b >> 2;
    int o = oc * 256 + threadIdx.x;
    int k0 = kc * 32;
    __shared__ float ts[32];
    if (threadIdx.x < 32) ts[threadIdx.x] = t[k0 + threadIdx.x];
    __syncthreads();
    float acc = (kc == 0) ? b3[o] : 0.f;
    #pragma unroll 8
    for (int k = 0; k < 32; k++) acc = fmaf(ts[k], W3[(size_t)(k0 + k) * 1024 + o], acc);
    atomicAdd(&g[o], acc);
}

// ---------- K8: head layer-1 partial matvecs (bias/relu deferred) ----------
// grid 256 = oc(16) x kc(16); outputs 0..2047 -> hv_raw, 2048..4095 -> ha_raw
__global__ __launch_bounds__(256) void k_heads1(const float* __restrict__ g,
                                                const float* __restrict__ Wv1,
                                                const float* __restrict__ Wa1,
                                                float* __restrict__ hv_raw,
                                                float* __restrict__ ha_raw) {
    int b = blockIdx.x;
    int oc = b >> 4, kc = b & 15;
    int idx = oc * 256 + threadIdx.x;  // 0..4095
    int k0 = kc * 64;
    __shared__ float gs[64];
    if (threadIdx.x < 64) gs[threadIdx.x] = g[k0 + threadIdx.x];
    __syncthreads();
    const float* W; float* outp; int o;
    if (idx < 2048) { W = Wv1; outp = hv_raw; o = idx; }
    else            { W = Wa1; outp = ha_raw; o = idx - 2048; }
    float acc = 0.f;
    #pragma unroll 8
    for (int k = 0; k < 64; k++) acc = fmaf(gs[k], W[(size_t)(k0 + k) * 2048 + o], acc);
    atomicAdd(&outp[o], acc);
}

// ---------- K9: head layer-2: a partials (128 blocks) + v (1 block) ----------
__global__ __launch_bounds__(256) void k_heads2(const float* __restrict__ hv_raw,
                                                const float* __restrict__ bv1,
                                                const float* __restrict__ ha_raw,
                                                const float* __restrict__ ba1,
                                                const float* __restrict__ Wv2,
                                                const float* __restrict__ bv2,
                                                const float* __restrict__ Wa2,
                                                float* __restrict__ a_acc,
                                                float* __restrict__ v) {
    int b = blockIdx.x;
    int tid = threadIdx.x;
    if (b < 128) {
        int oc = b >> 5, kc = b & 31;   // oc 0..3, kc 0..31
        int k0 = kc * 64;
        __shared__ float hs[64];
        if (tid < 64) hs[tid] = fmaxf(ha_raw[k0 + tid] + ba1[k0 + tid], 0.f);
        __syncthreads();
        int o = oc * 256 + tid;  // 0..1023
        if (o < 1000) {
            float acc = 0.f;
            #pragma unroll 8
            for (int k = 0; k < 64; k++)
                acc = fmaf(hs[k], Wa2[(size_t)(k0 + k) * 1000 + o], acc);
            atomicAdd(&a_acc[o], acc);
        }
    } else {
        __shared__ float red[256];
        float acc = 0.f;
        for (int k = tid; k < 2048; k += 256)
            acc = fmaf(fmaxf(hv_raw[k] + bv1[k], 0.f), Wv2[k], acc);
        red[tid] = acc;
        __syncthreads();
        for (int s = 128; s >= 1; s >>= 1) {
            if (tid < s) red[tid] += red[tid + s];
            __syncthreads();
        }
        if (tid == 0) *v = red[0] + bv2[0];
    }
}

// ---------- K10: final: out = v + (a - mean(a)) ----------
__global__ __launch_bounds__(1024) void k_final(const float* __restrict__ a_acc,
                                                const float* __restrict__ ba2,
                                                const float* __restrict__ vptr,
                                                float* __restrict__ out) {
    __shared__ float red[1024];
    int tid = threadIdx.x;
    float ai = (tid < 1000) ? a_acc[tid] + ba2[tid] : 0.f;
    red[tid] = ai;
    __syncthreads();
    for (int s = 512; s >= 1; s >>= 1) {
        if (tid < s) red[tid] += red[tid + s];
        __syncthreads();
    }
    float amean = red[0] * (1.0f / 1000.0f);
    if (tid < 1000) out[tid] = vptr[0] + ai - amean;
}

extern "C" void kernel_launch(void* const* d_in, const int* in_sizes, int n_in,
                              void* d_out, int out_size, void* d_ws, size_t ws_size,
                              hipStream_t stream) {
    const float* x   = (const float*)d_in[0];
    const float* ef  = (const float*)d_in[1];
    const float* W1  = (const float*)d_in[2];
    const float* b1  = (const float*)d_in[3];
    const float* W2  = (const float*)d_in[4];
    const float* b2  = (const float*)d_in[5];
    const float* W3  = (const float*)d_in[6];
    const float* b3  = (const float*)d_in[7];
    const float* Wv1 = (const float*)d_in[8];
    const float* bv1 = (const float*)d_in[9];
    const float* Wv2 = (const float*)d_in[10];
    const float* bv2 = (const float*)d_in[11];
    const float* Wa1 = (const float*)d_in[12];
    const float* ba1 = (const float*)d_in[13];
    const float* Wa2 = (const float*)d_in[14];
    const float* ba2 = (const float*)d_in[15];
    const int*   src = (const int*)d_in[16];
    const int*   dst = (const int*)d_in[17];
    float* out = (float*)d_out;

    char* ws = (char*)d_ws;
    size_t off = 0;
    auto alloc = [&](size_t bytes) -> void* {
        void* p = ws + off;
        off = (off + bytes + 255) & ~(size_t)255;
        return p;
    };
    // --- zeroed region (accumulators) ---
    int*   deg_out = (int*)  alloc(NN * 4);
    int*   deg_in  = (int*)  alloc(NN * 4);
    int*   cursor  = (int*)  alloc(NN * 4);
    float* c       = (float*)alloc(NN * 4);
    float* t       = (float*)alloc(512 * 4);
    float* g       = (float*)alloc(1024 * 4);
    float* hv_raw  = (float*)alloc(2048 * 4);
    float* ha_raw  = (float*)alloc(2048 * 4);
    float* a_acc   = (float*)alloc(1024 * 4);
    size_t zero_bytes = off;
    // --- non-zeroed scratch ---
    int*   rowptr  = (int*)  alloc((NN + 1) * 4);
    int*   eidx    = (int*)  alloc((size_t)NE * 4);
    float* h1s     = (float*)alloc((size_t)NN * 11 * 4);
    float* agg2    = (float*)alloc((size_t)NN * 11 * 4);
    float* v       = (float*)alloc(256);

    hipMemsetAsync(d_ws, 0, zero_bytes, stream);

    k_deg<<<(NE + 255) / 256, 256, 0, stream>>>(src, dst, deg_out, deg_in);
    k_scan<<<1, 1024, 0, stream>>>(deg_in, rowptr);
    k_scatter<<<(NE + 255) / 256, 256, 0, stream>>>(dst, rowptr, cursor, eidx);
    k_conv1g<<<(NN + 255) / 256, 256, 0, stream>>>(x, src, eidx, rowptr, deg_out, deg_in,
                                                   W1, b1, h1s, c);
    k_agg2g<<<(NN + 22) / 23, 256, 0, stream>>>(h1s, ef, src, eidx, rowptr, agg2);
    k_conv2_reduce<<<(NN + NPB - 1) / NPB, 512, 0, stream>>>(agg2, W2, b2, c, deg_out, deg_in, t);
    k_g<<<64, 256, 0, stream>>>(t, W3, b3, g);
    k_heads1<<<256, 256, 0, stream>>>(g, Wv1, Wa1, hv_raw, ha_raw);
    k_heads2<<<129, 256, 0, stream>>>(hv_raw, bv1, ha_raw, ba1, Wv2, bv2, Wa2, a_acc, v);
    k_final<<<1, 1024, 0, stream>>>(a_acc, ba2, v, out);
}

// Round 3
// 205.605 us; speedup vs baseline: 1.6297x; 1.4032x over previous
//
#include <hip/hip_runtime.h>

#define NN 50000
#define NE 150000
#define NB 196  // ceil(NN/256)

// ---------- K1: degree histograms (self-loop handled as +1 at read) ----------
__global__ __launch_bounds__(256) void k_deg(const int* __restrict__ src,
                                             const int* __restrict__ dst,
                                             int* __restrict__ deg_out,
                                             int* __restrict__ deg_in) {
    int e = blockIdx.x * 256 + threadIdx.x;
    if (e < NE) {
        atomicAdd(&deg_out[src[e]], 1);
        atomicAdd(&deg_in[dst[e]], 1);
    }
}

// ---------- K2a: per-block partial sums of deg_in and deg_out ----------
__global__ __launch_bounds__(256) void k_bsum(const int* __restrict__ deg_in,
                                              const int* __restrict__ deg_out,
                                              int* __restrict__ bsum_in,
                                              int* __restrict__ bsum_out) {
    __shared__ int si[256], so[256];
    int t = threadIdx.x;
    int idx = blockIdx.x * 256 + t;
    si[t] = (idx < NN) ? deg_in[idx] : 0;
    so[t] = (idx < NN) ? deg_out[idx] : 0;
    __syncthreads();
    for (int off = 128; off >= 1; off >>= 1) {
        if (t < off) { si[t] += si[t + off]; so[t] += so[t + off]; }
        __syncthreads();
    }
    if (t == 0) { bsum_in[blockIdx.x] = si[0]; bsum_out[blockIdx.x] = so[0]; }
}

// ---------- K2b: per-block offset + intra-block exclusive scan -> rowptrs ----------
__global__ __launch_bounds__(256) void k_rowptr(const int* __restrict__ deg_in,
                                                const int* __restrict__ deg_out,
                                                const int* __restrict__ bsum_in,
                                                const int* __restrict__ bsum_out,
                                                int* __restrict__ rp_in,
                                                int* __restrict__ rp_out) {
    __shared__ int si[256], so[256];
    int b = blockIdx.x, t = threadIdx.x;
    // block offset = sum of bsums of preceding blocks
    si[t] = (t < b) ? bsum_in[t] : 0;
    so[t] = (t < b) ? bsum_out[t] : 0;
    __syncthreads();
    for (int off = 128; off >= 1; off >>= 1) {
        if (t < off) { si[t] += si[t + off]; so[t] += so[t + off]; }
        __syncthreads();
    }
    int off_in = si[0], off_out = so[0];
    __syncthreads();
    // intra-block inclusive scan of own chunk
    int idx = b * 256 + t;
    int di = (idx < NN) ? deg_in[idx] : 0;
    int dq = (idx < NN) ? deg_out[idx] : 0;
    si[t] = di; so[t] = dq;
    __syncthreads();
    for (int off = 1; off < 256; off <<= 1) {
        int a = (t >= off) ? si[t - off] : 0;
        int c2 = (t >= off) ? so[t - off] : 0;
        __syncthreads();
        si[t] += a; so[t] += c2;
        __syncthreads();
    }
    if (idx < NN) {
        rp_in[idx]  = off_in  + si[t] - di;   // exclusive
        rp_out[idx] = off_out + so[t] - dq;
    }
    if (b == 0 && t == 0) { rp_in[NN] = NE; rp_out[NN] = NE; }
}

// ---------- K3: scatter edges into dst-sorted (eidx) and src-sorted (nbr=dst) buckets ----------
__global__ __launch_bounds__(256) void k_scatter(const int* __restrict__ src,
                                                 const int* __restrict__ dst,
                                                 const int* __restrict__ rp_in,
                                                 const int* __restrict__ rp_out,
                                                 int* __restrict__ cur_in,
                                                 int* __restrict__ cur_out,
                                                 int* __restrict__ eidx_in,
                                                 int* __restrict__ nbr_out) {
    int e = blockIdx.x * 256 + threadIdx.x;
    if (e >= NE) return;
    int s = src[e], d = dst[e];
    int pi = rp_in[d] + atomicAdd(&cur_in[d], 1);
    eidx_in[pi] = e;
    int po = rp_out[s] + atomicAdd(&cur_out[s], 1);
    nbr_out[po] = d;
}

// ---------- K4: conv1 via CSR gathers + fused 4->11 matvec/relu; c as plain store ----------
__global__ __launch_bounds__(256) void k_conv1g(const float* __restrict__ x,
                                                const int* __restrict__ src,
                                                const int* __restrict__ eidx_in,
                                                const int* __restrict__ rp_in,
                                                const int* __restrict__ nbr_out,
                                                const int* __restrict__ rp_out,
                                                const int* __restrict__ deg_out,
                                                const int* __restrict__ deg_in,
                                                const float* __restrict__ W1,
                                                const float* __restrict__ b1,
                                                float* __restrict__ h1s,
                                                float* __restrict__ c) {
    int n = blockIdx.x * 256 + threadIdx.x;
    if (n >= NN) return;
    float din  = rsqrtf((float)(deg_in[n] + 1));
    float dout = rsqrtf((float)(deg_out[n] + 1));
    // self-loop contribution
    const float4 xn = ((const float4*)x)[n];
    float a0 = xn.x * dout, a1 = xn.y * dout, a2 = xn.z * dout, a3 = xn.w * dout;
    int beg = rp_in[n], end = rp_in[n + 1];
    for (int p = beg; p < end; p++) {
        int e = eidx_in[p];
        int s = src[e];
        float ds = rsqrtf((float)(deg_out[s] + 1));
        float4 xs = ((const float4*)x)[s];
        a0 = fmaf(xs.x, ds, a0);
        a1 = fmaf(xs.y, ds, a1);
        a2 = fmaf(xs.z, ds, a2);
        a3 = fmaf(xs.w, ds, a3);
    }
    // c[n] = din_n (self loop) + sum over out-edges of din_dst
    float cacc = din;
    int ob = rp_out[n], oe = rp_out[n + 1];
    for (int p = ob; p < oe; p++) {
        int d = nbr_out[p];
        cacc += rsqrtf((float)(deg_in[d] + 1));
    }
    c[n] = cacc;
    #pragma unroll
    for (int j = 0; j < 11; j++) {
        float y = a0 * W1[0 * 11 + j] + a1 * W1[1 * 11 + j] +
                  a2 * W1[2 * 11 + j] + a3 * W1[3 * 11 + j];
        y = fmaxf(fmaf(y, din, b1[j]), 0.f);
        h1s[n * 11 + j] = y * dout;
    }
}

// ---------- K5: conv2 aggregation via CSR gather (self loops ef=0 -> skip) ----------
// thread = (node, feature j); 23 nodes per 256-thread block
__global__ __launch_bounds__(256) void k_agg2g(const float* __restrict__ h1s,
                                               const float* __restrict__ ef,
                                               const int* __restrict__ src,
                                               const int* __restrict__ eidx_in,
                                               const int* __restrict__ rp_in,
                                               float* __restrict__ agg2) {
    int tid = threadIdx.x;
    if (tid >= 253) return;
    int n = blockIdx.x * 23 + tid / 11;
    int j = tid % 11;
    if (n >= NN) return;
    int beg = rp_in[n], end = rp_in[n + 1];
    float acc = 0.f;
    for (int p = beg; p < end; p++) {
        int e = eidx_in[p];
        int s = src[e];
        acc = fmaf(h1s[s * 11 + j], ef[e * 11 + j], acc);
    }
    agg2[n * 11 + j] = acc;
}

// ---------- K6: conv2 matvec+relu fused with weighted mean-reduction into t[512] ----------
#define NPB 64
__global__ __launch_bounds__(512) void k_conv2_reduce(const float* __restrict__ agg2,
                                                      const float* __restrict__ W2,
                                                      const float* __restrict__ b2,
                                                      const float* __restrict__ c,
                                                      const int* __restrict__ deg_out,
                                                      const int* __restrict__ deg_in,
                                                      float* __restrict__ t) {
    __shared__ float tile[NPB * 11];
    __shared__ float din_sh[NPB], w_sh[NPB];
    int n0 = blockIdx.x * NPB;
    int tid = threadIdx.x;
    for (int i = tid; i < NPB * 11; i += 512) {
        int gi = n0 * 11 + i;
        tile[i] = (gi < NN * 11) ? agg2[gi] : 0.f;
    }
    if (tid < NPB) {
        int node = n0 + tid;
        if (node < NN) {
            din_sh[tid] = rsqrtf((float)(deg_in[node] + 1));
            w_sh[tid]   = c[node] * rsqrtf((float)(deg_out[node] + 1)) * (1.0f / NN);
        } else { din_sh[tid] = 0.f; w_sh[tid] = 0.f; }
    }
    __syncthreads();
    float w[11];
    #pragma unroll
    for (int j = 0; j < 11; j++) w[j] = W2[j * 512 + tid];
    float bias = b2[tid];
    float acc = 0.f;
    for (int i = 0; i < NPB; i++) {
        float dot = 0.f;
        #pragma unroll
        for (int j = 0; j < 11; j++) dot = fmaf(tile[i * 11 + j], w[j], dot);
        float y = fmaxf(fmaf(dot, din_sh[i], bias), 0.f);
        acc = fmaf(w_sh[i], y, acc);
    }
    atomicAdd(&t[tid], acc);
}

// ---------- K7: g = t @ W3 + b3  (512x1024 matvec, k-split 16 ways) ----------
__global__ __launch_bounds__(256) void k_g(const float* __restrict__ t,
                                           const float* __restrict__ W3,
                                           const float* __restrict__ b3,
                                           float* __restrict__ g) {
    int b = blockIdx.x;          // 64 = 4 oc x 16 kc
    int oc = b & 3, kc = b >> 2;
    int o = oc * 256 + threadIdx.x;
    int k0 = kc * 32;
    __shared__ float ts[32];
    if (threadIdx.x < 32) ts[threadIdx.x] = t[k0 + threadIdx.x];
    __syncthreads();
    float acc = (kc == 0) ? b3[o] : 0.f;
    #pragma unroll 8
    for (int k = 0; k < 32; k++) acc = fmaf(ts[k], W3[(size_t)(k0 + k) * 1024 + o], acc);
    atomicAdd(&g[o], acc);
}

// ---------- K8: head layer-1 partial matvecs (bias/relu deferred) ----------
// grid 256 = oc(16) x kc(16); outputs 0..2047 -> hv_raw, 2048..4095 -> ha_raw
__global__ __launch_bounds__(256) void k_heads1(const float* __restrict__ g,
                                                const float* __restrict__ Wv1,
                                                const float* __restrict__ Wa1,
                                                float* __restrict__ hv_raw,
                                                float* __restrict__ ha_raw) {
    int b = blockIdx.x;
    int oc = b >> 4, kc = b & 15;
    int idx = oc * 256 + threadIdx.x;  // 0..4095
    int k0 = kc * 64;
    __shared__ float gs[64];
    if (threadIdx.x < 64) gs[threadIdx.x] = g[k0 + threadIdx.x];
    __syncthreads();
    const float* W; float* outp; int o;
    if (idx < 2048) { W = Wv1; outp = hv_raw; o = idx; }
    else            { W = Wa1; outp = ha_raw; o = idx - 2048; }
    float acc = 0.f;
    #pragma unroll 8
    for (int k = 0; k < 64; k++) acc = fmaf(gs[k], W[(size_t)(k0 + k) * 2048 + o], acc);
    atomicAdd(&outp[o], acc);
}

// ---------- K9: head layer-2: a partials (128 blocks) + v (1 block) ----------
__global__ __launch_bounds__(256) void k_heads2(const float* __restrict__ hv_raw,
                                                const float* __restrict__ bv1,
                                                const float* __restrict__ ha_raw,
                                                const float* __restrict__ ba1,
                                                const float* __restrict__ Wv2,
                                                const float* __restrict__ bv2,
                                                const float* __restrict__ Wa2,
                                                float* __restrict__ a_acc,
                                                float* __restrict__ v) {
    int b = blockIdx.x;
    int tid = threadIdx.x;
    if (b < 128) {
        int oc = b >> 5, kc = b & 31;   // oc 0..3, kc 0..31
        int k0 = kc * 64;
        __shared__ float hs[64];
        if (tid < 64) hs[tid] = fmaxf(ha_raw[k0 + tid] + ba1[k0 + tid], 0.f);
        __syncthreads();
        int o = oc * 256 + tid;  // 0..1023
        if (o < 1000) {
            float acc = 0.f;
            #pragma unroll 8
            for (int k = 0; k < 64; k++)
                acc = fmaf(hs[k], Wa2[(size_t)(k0 + k) * 1000 + o], acc);
            atomicAdd(&a_acc[o], acc);
        }
    } else {
        __shared__ float red[256];
        float acc = 0.f;
        for (int k = tid; k < 2048; k += 256)
            acc = fmaf(fmaxf(hv_raw[k] + bv1[k], 0.f), Wv2[k], acc);
        red[tid] = acc;
        __syncthreads();
        for (int s = 128; s >= 1; s >>= 1) {
            if (tid < s) red[tid] += red[tid + s];
            __syncthreads();
        }
        if (tid == 0) *v = red[0] + bv2[0];
    }
}

// ---------- K10: final: out = v + (a - mean(a)) ----------
__global__ __launch_bounds__(1024) void k_final(const float* __restrict__ a_acc,
                                                const float* __restrict__ ba2,
                                                const float* __restrict__ vptr,
                                                float* __restrict__ out) {
    __shared__ float red[1024];
    int tid = threadIdx.x;
    float ai = (tid < 1000) ? a_acc[tid] + ba2[tid] : 0.f;
    red[tid] = ai;
    __syncthreads();
    for (int s = 512; s >= 1; s >>= 1) {
        if (tid < s) red[tid] += red[tid + s];
        __syncthreads();
    }
    float amean = red[0] * (1.0f / 1000.0f);
    if (tid < 1000) out[tid] = vptr[0] + ai - amean;
}

extern "C" void kernel_launch(void* const* d_in, const int* in_sizes, int n_in,
                              void* d_out, int out_size, void* d_ws, size_t ws_size,
                              hipStream_t stream) {
    const float* x   = (const float*)d_in[0];
    const float* ef  = (const float*)d_in[1];
    const float* W1  = (const float*)d_in[2];
    const float* b1  = (const float*)d_in[3];
    const float* W2  = (const float*)d_in[4];
    const float* b2  = (const float*)d_in[5];
    const float* W3  = (const float*)d_in[6];
    const float* b3  = (const float*)d_in[7];
    const float* Wv1 = (const float*)d_in[8];
    const float* bv1 = (const float*)d_in[9];
    const float* Wv2 = (const float*)d_in[10];
    const float* bv2 = (const float*)d_in[11];
    const float* Wa1 = (const float*)d_in[12];
    const float* ba1 = (const float*)d_in[13];
    const float* Wa2 = (const float*)d_in[14];
    const float* ba2 = (const float*)d_in[15];
    const int*   src = (const int*)d_in[16];
    const int*   dst = (const int*)d_in[17];
    float* out = (float*)d_out;

    char* ws = (char*)d_ws;
    size_t off = 0;
    auto alloc = [&](size_t bytes) -> void* {
        void* p = ws + off;
        off = (off + bytes + 255) & ~(size_t)255;
        return p;
    };
    // --- zeroed region (accumulators) ---
    int*   deg_out = (int*)  alloc(NN * 4);
    int*   deg_in  = (int*)  alloc(NN * 4);
    int*   cur_in  = (int*)  alloc(NN * 4);
    int*   cur_out = (int*)  alloc(NN * 4);
    float* t       = (float*)alloc(512 * 4);
    float* g       = (float*)alloc(1024 * 4);
    float* hv_raw  = (float*)alloc(2048 * 4);
    float* ha_raw  = (float*)alloc(2048 * 4);
    float* a_acc   = (float*)alloc(1024 * 4);
    size_t zero_bytes = off;
    // --- non-zeroed scratch ---
    int*   bsum_in  = (int*)  alloc(NB * 4);
    int*   bsum_out = (int*)  alloc(NB * 4);
    int*   rp_in    = (int*)  alloc((NN + 1) * 4);
    int*   rp_out   = (int*)  alloc((NN + 1) * 4);
    int*   eidx_in  = (int*)  alloc((size_t)NE * 4);
    int*   nbr_out  = (int*)  alloc((size_t)NE * 4);
    float* c        = (float*)alloc(NN * 4);
    float* h1s      = (float*)alloc((size_t)NN * 11 * 4);
    float* agg2     = (float*)alloc((size_t)NN * 11 * 4);
    float* v        = (float*)alloc(256);

    hipMemsetAsync(d_ws, 0, zero_bytes, stream);

    k_deg<<<(NE + 255) / 256, 256, 0, stream>>>(src, dst, deg_out, deg_in);
    k_bsum<<<NB, 256, 0, stream>>>(deg_in, deg_out, bsum_in, bsum_out);
    k_rowptr<<<NB, 256, 0, stream>>>(deg_in, deg_out, bsum_in, bsum_out, rp_in, rp_out);
    k_scatter<<<(NE + 255) / 256, 256, 0, stream>>>(src, dst, rp_in, rp_out,
                                                    cur_in, cur_out, eidx_in, nbr_out);
    k_conv1g<<<(NN + 255) / 256, 256, 0, stream>>>(x, src, eidx_in, rp_in, nbr_out, rp_out,
                                                   deg_out, deg_in, W1, b1, h1s, c);
    k_agg2g<<<(NN + 22) / 23, 256, 0, stream>>>(h1s, ef, src, eidx_in, rp_in, agg2);
    k_conv2_reduce<<<(NN + NPB - 1) / NPB, 512, 0, stream>>>(agg2, W2, b2, c, deg_out, deg_in, t);
    k_g<<<64, 256, 0, stream>>>(t, W3, b3, g);
    k_heads1<<<256, 256, 0, stream>>>(g, Wv1, Wa1, hv_raw, ha_raw);
    k_heads2<<<129, 256, 0, stream>>>(hv_raw, bv1, ha_raw, ba1, Wv2, bv2, Wa2, a_acc, v);
    k_final<<<1, 1024, 0, stream>>>(a_acc, ba2, v, out);
}